// Round 6
// baseline (369.823 us; speedup 1.0000x reference)
//
#include <hip/hip_runtime.h>
#include <hip/hip_cooperative_groups.h>
#include <hip/hip_bf16.h>
#include <stdint.h>

namespace cg = cooperative_groups;

// Problem constants (B, C, D, H, W) = (2, 128, 16, 64, 64)
#define BB  2
#define CC  128
#define NNN 65536          // D*H*W

typedef __bf16 bf16x8 __attribute__((ext_vector_type(8)));
typedef float  f32x16 __attribute__((ext_vector_type(16)));

__device__ __forceinline__ uint16_t f2bf(float f) {
    uint32_t u = __float_as_uint(f);
    u = (u + 0x7fffu + ((u >> 16) & 1u)) >> 16;   // RNE
    return (uint16_t)u;
}
__device__ __forceinline__ uint32_t pack2(float a, float b) {
    return (uint32_t)f2bf(a) | ((uint32_t)f2bf(b) << 16);
}

// ---------------------------------------------------------------------------
// ONE cooperative kernel, 512 blocks x 256 threads, 64 KB dynamic LDS
// (2 blocks/CU -> all 512 co-resident).  Three phases with grid.sync():
//   P1 gram:   per-block 256-n chunk, convert fp32->bf16 in regs, LDS
//              frag-ordered dbuf, 16 MFMA/stage, write 128x128 fp32 partial
//   P2 reduce: blocks 0..255 reduce 256 partials -> energy row, softmax of
//              (rowmax - e), gamma pre-scaled, emit bf16 att
//   P3 AV:     stage 256n x 128c channel-packed bf16 tile (XOR swizzle),
//              A-frags (att) from global (L2), B-frags single ds_read_b128,
//              out = acc + x residual (exact fp32)
// ---------------------------------------------------------------------------
#define GCH  256
#define GST  64
#define GPAD 130
#define AVN  256

__global__ __launch_bounds__(256, 2) void fused_kernel(
        const float* __restrict__ x, float* __restrict__ partial,
        const float* __restrict__ gamma, uint16_t* __restrict__ attw,
        float* __restrict__ out) {
    extern __shared__ char smem[];        // 65536 B
    cg::grid_group grid = cg::this_grid();

    const int bid = blockIdx.x;           // [0,512)
    const int t   = threadIdx.x;
    const int w = t >> 6, l = t & 63, h = l >> 5, ln = l & 31;

    // ======================= Phase 1: Gram =======================
    {
        uint4* lds = (uint4*)smem;        // [2][8*GPAD] = 33.3 KB
        const int b = bid >> 8, chunk = bid & 255;
        const int n0 = chunk * GCH;
        const float* xb = x + (size_t)b * CC * NNN;
        const int sc = t >> 3;            // c base [0,32), + 32p
        const int sg = t & 7;             // n-oct within stage

        f32x16 acc[4];
#pragma unroll
        for (int j = 0; j < 4; ++j)
#pragma unroll
            for (int r = 0; r < 16; ++r) acc[j][r] = 0.0f;

        float4 va[2][4], vb[2][4];        // 2-stage register prefetch
#pragma unroll
        for (int s2 = 0; s2 < 2; ++s2)
#pragma unroll
            for (int p = 0; p < 4; ++p) {
                const float* gp = xb + (size_t)(sc + 32 * p) * NNN + n0 + s2 * GST + sg * 8;
                va[s2][p] = *(const float4*)(gp);
                vb[s2][p] = *(const float4*)(gp + 4);
            }

        for (int st = 0; st < 4; ++st) {
            const int set = st & 1;
            uint4* ld = lds + set * (8 * GPAD);
#pragma unroll
            for (int p = 0; p < 4; ++p) {
                uint4 u;
                u.x = pack2(va[set][p].x, va[set][p].y);
                u.y = pack2(va[set][p].z, va[set][p].w);
                u.z = pack2(vb[set][p].x, vb[set][p].y);
                u.w = pack2(vb[set][p].z, vb[set][p].w);
                ld[sg * GPAD + sc + 32 * p] = u;
            }
            if (st + 2 < 4) {
#pragma unroll
                for (int p = 0; p < 4; ++p) {
                    const float* gp = xb + (size_t)(sc + 32 * p) * NNN + n0 + (st + 2) * GST + sg * 8;
                    va[set][p] = *(const float4*)(gp);
                    vb[set][p] = *(const float4*)(gp + 4);
                }
            }
            __syncthreads();              // single barrier per stage
#pragma unroll
            for (int s = 0; s < 4; ++s) {
                bf16x8 fa = *(const bf16x8*)&ld[(2 * s + h) * GPAD + 32 * w + ln];
#pragma unroll
                for (int j = 0; j < 4; ++j) {
                    bf16x8 fb = *(const bf16x8*)&ld[(2 * s + h) * GPAD + 32 * j + ln];
                    acc[j] = __builtin_amdgcn_mfma_f32_32x32x16_bf16(fa, fb, acc[j], 0, 0, 0);
                }
            }
            __syncthreads();              // protect dbuf re-write (coop: cheap)
        }

        float* pb = partial + (size_t)bid * (CC * CC);
#pragma unroll
        for (int j = 0; j < 4; ++j)
#pragma unroll
            for (int r = 0; r < 16; ++r) {
                int row = 32 * w + (r & 3) + 8 * (r >> 2) + 4 * h;   // verified C/D map
                pb[row * CC + 32 * j + ln] = acc[j][r];
            }
    }

    __threadfence();
    grid.sync();

    // =================== Phase 2: reduce + softmax ===================
    if (bid < BB * CC) {
        const int row = bid;              // b*128 + i
        const int b = row >> 7, i = row & 127;
        const int j = t & 127, ph = t >> 7;

        const float* base = partial + ((size_t)(b * 256 + ph * 128)) * (CC * CC)
                          + (size_t)i * CC + j;
        float s0=0,s1=0,s2=0,s3=0,s4=0,s5=0,s6=0,s7=0;
        for (int p = 0; p < 128; p += 8) {
            s0 += base[(size_t)(p + 0) * (CC * CC)];
            s1 += base[(size_t)(p + 1) * (CC * CC)];
            s2 += base[(size_t)(p + 2) * (CC * CC)];
            s3 += base[(size_t)(p + 3) * (CC * CC)];
            s4 += base[(size_t)(p + 4) * (CC * CC)];
            s5 += base[(size_t)(p + 5) * (CC * CC)];
            s6 += base[(size_t)(p + 6) * (CC * CC)];
            s7 += base[(size_t)(p + 7) * (CC * CC)];
        }
        const float sp = ((s0 + s1) + (s2 + s3)) + ((s4 + s5) + (s6 + s7));

        float* red = (float*)smem;        // [256]
        float* m   = (float*)smem + 256;  // [128]
        red[t] = sp; __syncthreads();
        const float e = red[j] + red[j + 128];

        if (ph == 0) m[j] = e;
        __syncthreads();
        for (int s = 64; s > 0; s >>= 1) {
            if (ph == 0 && j < s) m[j] = fmaxf(m[j], m[j + s]);
            __syncthreads();
        }
        const float M = m[0]; __syncthreads();
        const float v = M - e;
        if (ph == 0) m[j] = v;
        __syncthreads();
        for (int s = 64; s > 0; s >>= 1) {
            if (ph == 0 && j < s) m[j] = fmaxf(m[j], m[j + s]);
            __syncthreads();
        }
        const float m2 = m[0]; __syncthreads();
        const float pexp = __expf(v - m2);
        if (ph == 0) m[j] = pexp;
        __syncthreads();
        for (int s = 64; s > 0; s >>= 1) {
            if (ph == 0 && j < s) m[j] += m[j + s];
            __syncthreads();
        }
        const float sum = m[0];

        if (ph == 0)
            attw[(size_t)row * CC + j] = f2bf(gamma[0] * pexp / sum);
    }

    __threadfence();
    grid.sync();

    // ========================= Phase 3: AV =========================
    {
        uint4* xT = (uint4*)smem;         // [16][256] = 64 KB, n ^ ((n>>2)&7)
        const int b  = bid >> 8;
        const int n0 = (bid & 255) * AVN;
        const float* xb = x + (size_t)b * CC * NNN;

        // stage: 4 tasks/thread; task = (g2 = 4w+p, all 256 n via 64 lanes)
#pragma unroll
        for (int p = 0; p < 4; ++p) {
            const int g2 = 4 * w + p;
            float4 v[8];
#pragma unroll
            for (int j = 0; j < 8; ++j)   // 8 channel rows, lane-coalesced
                v[j] = *(const float4*)(xb + (size_t)(8 * g2 + j) * NNN + n0 + 4 * l);
#pragma unroll
            for (int i = 0; i < 4; ++i) { // register transpose
                uint4 u;
                u.x = pack2(((const float*)&v[0])[i], ((const float*)&v[1])[i]);
                u.y = pack2(((const float*)&v[2])[i], ((const float*)&v[3])[i]);
                u.z = pack2(((const float*)&v[4])[i], ((const float*)&v[5])[i]);
                u.w = pack2(((const float*)&v[6])[i], ((const float*)&v[7])[i]);
                const int n  = 4 * l + i;
                const int nA = n ^ (l & 7);    // == n ^ ((n>>2)&7)
                xT[g2 * 256 + nA] = u;
            }
        }

        // preload A-frags (att rows for this wave's 32 channels), L2-hot
        bf16x8 fa[8];
        {
            const uint16_t* ab = attw + ((size_t)b * CC + 32 * w + ln) * CC + h * 8;
#pragma unroll
            for (int s = 0; s < 8; ++s)
                fa[s] = *(const bf16x8*)(ab + s * 16);
        }
        __syncthreads();

        // main loop: 8 n-subtiles of 32
#pragma unroll
        for (int jt = 0; jt < 8; ++jt) {
            const int n  = 32 * jt + ln;
            const int nA = n ^ ((ln >> 2) & 7);

            float xr[16];                 // residual prefetch (L2/L3-hot)
#pragma unroll
            for (int r = 0; r < 16; ++r) {
                int row = (r & 3) + 8 * (r >> 2) + 4 * h;
                xr[r] = xb[(size_t)(32 * w + row) * NNN + n0 + n];
            }

            f32x16 acc;
#pragma unroll
            for (int r = 0; r < 16; ++r) acc[r] = 0.0f;
#pragma unroll
            for (int s = 0; s < 8; ++s) {
                bf16x8 fb = *(const bf16x8*)&xT[(2 * s + h) * 256 + nA];
                acc = __builtin_amdgcn_mfma_f32_32x32x16_bf16(fa[s], fb, acc, 0, 0, 0);
            }
#pragma unroll
            for (int r = 0; r < 16; ++r) {
                int row = (r & 3) + 8 * (r >> 2) + 4 * h;
                out[((size_t)b * CC + 32 * w + row) * NNN + n0 + n] = acc[r] + xr[r];
            }
        }
    }
}

// ---------------------------------------------------------------------------
extern "C" void kernel_launch(void* const* d_in, const int* in_sizes, int n_in,
                              void* d_out, int out_size, void* d_ws, size_t ws_size,
                              hipStream_t stream) {
    const float* x     = (const float*)d_in[0];
    const float* gamma = (const float*)d_in[1];
    float* out = (float*)d_out;

    // workspace: partial 33.55 MB + att 64 KB
    float*    partial = (float*)d_ws;
    uint16_t* att     = (uint16_t*)(partial + (size_t)512 * CC * CC);

    void* args[] = { (void*)&x, (void*)&partial, (void*)&gamma,
                     (void*)&att, (void*)&out };
    hipLaunchCooperativeKernel((const void*)fused_kernel,
                               dim3(512), dim3(256), args, 65536, stream);
}

// Round 7
// 147.423 us; speedup vs baseline: 2.5086x; 2.5086x over previous
//
#include <hip/hip_runtime.h>
#include <hip/hip_bf16.h>
#include <stdint.h>

// Problem constants (B, C, D, H, W) = (2, 128, 16, 64, 64)
#define BB  2
#define CC  128
#define NNN 65536          // D*H*W

typedef __bf16 bf16x8 __attribute__((ext_vector_type(8)));
typedef float  f32x16 __attribute__((ext_vector_type(16)));

__device__ __forceinline__ uint16_t f2bf(float f) {
    uint32_t u = __float_as_uint(f);
    u = (u + 0x7fffu + ((u >> 16) & 1u)) >> 16;   // RNE
    return (uint16_t)u;
}
__device__ __forceinline__ uint32_t pack2(float a, float b) {
    return (uint32_t)f2bf(a) | ((uint32_t)f2bf(b) << 16);
}

// ---------------------------------------------------------------------------
// Kernel 1 (fused convert + Gram), 512 blocks x 512 threads (16 waves/CU):
//   8 waves: wave w8 = (row-strip = w8>>1, col-half = w8&1), acc = 2 x f32x16
//   (32 VGPRs/thread vs 64 in R5 -> fits 4 waves/SIMD).
//   Per-block 256-n chunk, fp32->bf16 in regs, LDS frag-ordered dbuf
//   ([n/8][c], pad 130), 4 stages x 64 n, 2-stage register prefetch,
//   ONE barrier per stage, 8 MFMA/wave/stage (64/block/stage).
// ---------------------------------------------------------------------------
#define GCH  256
#define GST  64
#define GPAD 130

__global__ __launch_bounds__(512, 4) void gram_kernel(const float* __restrict__ x,
        float* __restrict__ partial) {
    const int bid = blockIdx.x;            // [0,512)
    const int b   = bid >> 8, chunk = bid & 255;
    const int n0  = chunk * GCH;
    const int t   = threadIdx.x;           // [0,512)
    const int w8 = t >> 6, l = t & 63, h = l >> 5, ln = l & 31;
    const int strip = w8 >> 1, jh = w8 & 1;

    __shared__ uint4 lds[2][8 * GPAD];     // 2 x 16.6 KB

    const float* xb = x + (size_t)b * CC * NNN;
    const int sc = t >> 2;                 // channel row [0,128)
    const int sg = t & 3;                  // 16-n segment within stage

    f32x16 acc[2];
#pragma unroll
    for (int j = 0; j < 2; ++j)
#pragma unroll
        for (int r = 0; r < 16; ++r) acc[j][r] = 0.0f;

    float4 va[2][4];                       // 2-stage register prefetch (16 f4)
#pragma unroll
    for (int s2 = 0; s2 < 2; ++s2)
#pragma unroll
        for (int p = 0; p < 4; ++p)
            va[s2][p] = *(const float4*)(xb + (size_t)sc * NNN + n0 + s2 * GST + sg * 16 + 4 * p);

    for (int st = 0; st < 4; ++st) {
        const int set = st & 1;
        // ---- write stage (convert fp32 -> bf16), 2 uint4 per thread
#pragma unroll
        for (int q = 0; q < 2; ++q) {
            uint4 u;
            u.x = pack2(va[set][2 * q].x, va[set][2 * q].y);
            u.y = pack2(va[set][2 * q].z, va[set][2 * q].w);
            u.z = pack2(va[set][2 * q + 1].x, va[set][2 * q + 1].y);
            u.w = pack2(va[set][2 * q + 1].z, va[set][2 * q + 1].w);
            lds[set][(2 * sg + q) * GPAD + sc] = u;
        }
        // ---- prefetch stage st+2
        if (st + 2 < 4) {
#pragma unroll
            for (int p = 0; p < 4; ++p)
                va[set][p] = *(const float4*)(xb + (size_t)sc * NNN + n0 + (st + 2) * GST + sg * 16 + 4 * p);
        }
        __syncthreads();                   // single barrier per stage
#pragma unroll
        for (int s = 0; s < 4; ++s) {
            bf16x8 fa = *(const bf16x8*)&lds[set][(2 * s + h) * GPAD + 32 * strip + ln];
#pragma unroll
            for (int j = 0; j < 2; ++j) {
                bf16x8 fb = *(const bf16x8*)&lds[set][(2 * s + h) * GPAD + 32 * (2 * jh + j) + ln];
                acc[j] = __builtin_amdgcn_mfma_f32_32x32x16_bf16(fa, fb, acc[j], 0, 0, 0);
            }
        }
    }

    float* pb = partial + (size_t)bid * (CC * CC);
#pragma unroll
    for (int j = 0; j < 2; ++j)
#pragma unroll
        for (int r = 0; r < 16; ++r) {
            int row = 32 * strip + (r & 3) + 8 * (r >> 2) + 4 * h;   // verified C/D map
            pb[row * CC + 32 * (2 * jh + j) + ln] = acc[j][r];
        }
}

// ---------------------------------------------------------------------------
// Kernel 2: reduce 256 partials/batch -> energy row; softmax(max-e), gamma
// pre-scaled, emit bf16 att[b][c][k].  (unchanged from R5)
// ---------------------------------------------------------------------------
__global__ __launch_bounds__(256) void reduce_softmax_kernel(
        const float* __restrict__ partial, const float* __restrict__ gamma,
        uint16_t* __restrict__ attw) {
    const int row = blockIdx.x;            // b*128 + i
    const int b = row >> 7, i = row & 127;
    const int t = threadIdx.x;
    const int j = t & 127, ph = t >> 7;

    const float* base = partial + ((size_t)(b * 256 + ph * 128)) * (CC * CC)
                      + (size_t)i * CC + j;
    float s0=0,s1=0,s2=0,s3=0,s4=0,s5=0,s6=0,s7=0;
    for (int p = 0; p < 128; p += 8) {
        s0 += base[(size_t)(p + 0) * (CC * CC)];
        s1 += base[(size_t)(p + 1) * (CC * CC)];
        s2 += base[(size_t)(p + 2) * (CC * CC)];
        s3 += base[(size_t)(p + 3) * (CC * CC)];
        s4 += base[(size_t)(p + 4) * (CC * CC)];
        s5 += base[(size_t)(p + 5) * (CC * CC)];
        s6 += base[(size_t)(p + 6) * (CC * CC)];
        s7 += base[(size_t)(p + 7) * (CC * CC)];
    }
    const float sp = ((s0 + s1) + (s2 + s3)) + ((s4 + s5) + (s6 + s7));

    __shared__ float red[256];
    __shared__ float m[128];
    red[t] = sp; __syncthreads();
    const float e = red[j] + red[j + 128];

    if (ph == 0) m[j] = e;
    __syncthreads();
    for (int s = 64; s > 0; s >>= 1) {
        if (ph == 0 && j < s) m[j] = fmaxf(m[j], m[j + s]);
        __syncthreads();
    }
    const float M = m[0]; __syncthreads();
    const float v = M - e;
    if (ph == 0) m[j] = v;
    __syncthreads();
    for (int s = 64; s > 0; s >>= 1) {
        if (ph == 0 && j < s) m[j] = fmaxf(m[j], m[j + s]);
        __syncthreads();
    }
    const float m2 = m[0]; __syncthreads();
    const float pexp = __expf(v - m2);
    if (ph == 0) m[j] = pexp;
    __syncthreads();
    for (int s = 64; s > 0; s >>= 1) {
        if (ph == 0 && j < s) m[j] += m[j + s];
        __syncthreads();
    }
    const float sum = m[0];

    if (ph == 0)
        attw[(size_t)row * CC + j] = f2bf(gamma[0] * pexp / sum);
}

// ---------------------------------------------------------------------------
// Kernel 3 (AV), 512 blocks x 512 threads (16 waves/CU):
//   wave w8 = (row-strip = w8>>1, n-half = w8&1); per wave 4 n-subtiles.
//   Stage 256n x 128c channel-packed bf16 (XOR swizzle n^= (n>>2)&7):
//   staging writes AND frag reads conflict-free; B-frag = 1 ds_read_b128.
//   A-frags (att) preloaded from global (L2-resident). Residual exact fp32.
// ---------------------------------------------------------------------------
#define AVN 256

__global__ __launch_bounds__(512, 4) void av_kernel(const float* __restrict__ x,
        const uint16_t* __restrict__ attw, float* __restrict__ out) {
    const int bid = blockIdx.x;            // [0,512)
    const int b   = bid >> 8;
    const int n0  = (bid & 255) * AVN;
    const int t   = threadIdx.x;           // [0,512)
    const int w8 = t >> 6, l = t & 63, h = l >> 5, ln = l & 31;
    const int strip = w8 >> 1, nh = (w8 & 1) * 128;

    __shared__ uint4 xT[16 * 256];         // 64 KB: [c/8][n ^ ((n>>2)&7)]

    const float* xb = x + (size_t)b * CC * NNN;

    // ---- stage: 2 tasks/thread; task = (g2 = idx>>6, 4n at 4*(idx&63))
#pragma unroll
    for (int p = 0; p < 2; ++p) {
        const int idx = 512 * p + t;
        const int g2 = idx >> 6, li = idx & 63;
        float4 v[8];
#pragma unroll
        for (int j = 0; j < 8; ++j)        // 8 channel rows, lane-coalesced
            v[j] = *(const float4*)(xb + (size_t)(8 * g2 + j) * NNN + n0 + 4 * li);
#pragma unroll
        for (int i = 0; i < 4; ++i) {      // register transpose
            uint4 u;
            u.x = pack2(((const float*)&v[0])[i], ((const float*)&v[1])[i]);
            u.y = pack2(((const float*)&v[2])[i], ((const float*)&v[3])[i]);
            u.z = pack2(((const float*)&v[4])[i], ((const float*)&v[5])[i]);
            u.w = pack2(((const float*)&v[6])[i], ((const float*)&v[7])[i]);
            const int n  = 4 * li + i;
            const int nA = n ^ (li & 7);   // == n ^ ((n>>2)&7)
            xT[g2 * 256 + nA] = u;
        }
    }

    // ---- preload A-frags (att rows for this wave's 32 channels), L2-hot
    bf16x8 fa[8];
    {
        const uint16_t* ab = attw + ((size_t)b * CC + 32 * strip + ln) * CC + h * 8;
#pragma unroll
        for (int s = 0; s < 8; ++s)
            fa[s] = *(const bf16x8*)(ab + s * 16);
    }
    __syncthreads();

    // ---- main loop: 4 n-subtiles of 32 for this wave's n-half
#pragma unroll
    for (int jt = 0; jt < 4; ++jt) {
        const int n  = nh + 32 * jt + ln;
        const int nA = n ^ ((ln >> 2) & 7);

        float xr[16];                      // residual prefetch (L2-hot)
#pragma unroll
        for (int r = 0; r < 16; ++r) {
            int row = (r & 3) + 8 * (r >> 2) + 4 * h;
            xr[r] = xb[(size_t)(32 * strip + row) * NNN + n0 + n];
        }

        f32x16 acc;
#pragma unroll
        for (int r = 0; r < 16; ++r) acc[r] = 0.0f;
#pragma unroll
        for (int s = 0; s < 8; ++s) {
            bf16x8 fb = *(const bf16x8*)&xT[(2 * s + h) * 256 + nA];
            acc = __builtin_amdgcn_mfma_f32_32x32x16_bf16(fa[s], fb, acc, 0, 0, 0);
        }
#pragma unroll
        for (int r = 0; r < 16; ++r) {
            int row = (r & 3) + 8 * (r >> 2) + 4 * h;
            out[((size_t)b * CC + 32 * strip + row) * NNN + n0 + n] = acc[r] + xr[r];
        }
    }
}

// ---------------------------------------------------------------------------
extern "C" void kernel_launch(void* const* d_in, const int* in_sizes, int n_in,
                              void* d_out, int out_size, void* d_ws, size_t ws_size,
                              hipStream_t stream) {
    const float* x     = (const float*)d_in[0];
    const float* gamma = (const float*)d_in[1];
    float* out = (float*)d_out;

    // workspace: partial 33.55 MB + att 64 KB
    float*    partial = (float*)d_ws;
    uint16_t* att     = (uint16_t*)(partial + (size_t)512 * CC * CC);

    gram_kernel<<<BB * (NNN / GCH), 512, 0, stream>>>(x, partial);
    reduce_softmax_kernel<<<BB * CC, 256, 0, stream>>>(partial, gamma, att);
    av_kernel<<<BB * (NNN / AVN), 512, 0, stream>>>(x, att, out);
}